// Round 12
// baseline (361.708 us; speedup 1.0000x reference)
//
#include <hip/hip_runtime.h>
#include <math.h>
#include <type_traits>

typedef float f2 __attribute__((ext_vector_type(2)));
typedef float f4 __attribute__((ext_vector_type(4)));

#define DD 160
#define HH 160
#define WW 160
#define BB 4
#define KK 11
#define RAD 5
#define TH 16
#define TW 16
#define DCH 32
#define NPLANES (DCH + 2 * RAD)   // 42 planes per tile (loop padded to 44 = 4*11)
#define NDCH (DD / DCH)           // 5 depth chunks
#define HALO_H (TH + 2 * RAD)     // 26 halo rows
#define TS 16                     // tmp row stride; 16-lane groups tile all 32 banks
#define STAT (HALO_H * TS)        // 416 floats per convolved field plane

// Kernarg weight-pair table: gg[2x] = G(x-2), gg[2x+1] = G(x-3), where G(j) is
// the Gaussian tap for j in [0,10] and 0 outside. Scalar tap g[k] = gg[2*(k+2)].
struct GaussP { float gg[32]; };

template <int N> using ic = std::integral_constant<int, N>;

// R11 champion (4-field transform + XCD-chunked swizzle; FETCH 379->76 MB
// verified) with ONE delta: __launch_bounds__(128, 3).
// Session-measured launch-bounds semantics: 2nd arg w => allocator budget
// ~512/w regs/wave (w=2 -> 256 [R0..R11], w=4 -> 64 cap -> catastrophic spill
// [R1/R2]). w=3 -> ~170 cap; live set ~150-155 (ring 88 + prefetch 40 + misc)
// fits with margin -> no spill expected. If the HW wave-occupancy granularity
// admits 3 waves/SIMD at ~170 regs (the 64/128/256 steps leave this unprobed),
// occupancy 21 -> ~31% and the ~1400 cyc/plane mutual-stall window shrinks ~1/3.
// Sentinel: WRITE_SIZE >> 62.5 KB means the allocator spilled -> revert.
__global__ __launch_bounds__(128, 3)
void ssim3d_kernel(const float* __restrict__ img1,
                   const float* __restrict__ img2,
                   float* __restrict__ out, GaussP gp)
{
    __shared__ float tmpA[4 * STAT];   // plane double buffer (pointer swap), 13.3 KB
    __shared__ float tmpB[4 * STAT];
    __shared__ float wsum[2];

    const int tid = threadIdx.x;        // 128 threads = 2 waves
    const int xc = tid & 7;             // phase-2: col pair 2xc, 2xc+1
    const int ty = tid >> 3;            // phase-2: row 0..15
    const int lane = tid & 63;          // phase-1: 52 tasks per wave (balanced)
    const int task = lane + (tid >> 6) * 52;
    const bool p1act = lane < 52;
    const int p1r = task >> 2;          // halo row 0..25
    const int p1q = task & 3;           // quad index

    // XCD-chunked swizzle (bijective: 2000 blocks, 2000 % 8 == 0).
    const int blk0 = blockIdx.x;
    const int blk = (blk0 & 7) * 250 + (blk0 >> 3);
    const int bw = blk % 10;
    const int bh = (blk / 10) % 10;
    const int bd = (blk / 100) % NDCH;
    const int bb = blk / (100 * NDCH);

    const int oh0 = bh * TH, ow0 = bw * TW, od0 = bd * DCH;
    const float* base1 = img1 + (size_t)bb * DD * HH * WW;
    const float* base2 = img2 + (size_t)bb * DD * HH * WW;

    // Static D-ring: slot s accumulates output plane q with q % 11 == s.
    f2 aU[KK], aV[KK], aA[KK], aB[KK];
#pragma unroll
    for (int i = 0; i < KK; ++i) { aU[i]=0.f; aV[i]=0.f; aA[i]=0.f; aB[i]=0.f; }

    f2 lsum = 0.f;

    // Phase-1 per-thread constants.
    const int gh = oh0 - RAD + p1r;
    const bool rowok = p1act && ((unsigned)gh < (unsigned)HH);
    const int gc0 = ow0 + 4 * p1q - 8;                    // first loaded col, 16B aligned
    const size_t rowoff = (size_t)((unsigned)gh < (unsigned)HH ? gh : 0) * WW;

    // Register prefetch for the next plane (20 cols per thread, both images).
    f4 pa[5], pb[5];
#pragma unroll
    for (int j = 0; j < 5; ++j) { pa[j] = (f4)0.f; pb[j] = (f4)0.f; }

    float* twr = tmpA;   // written (and read) this plane
    float* trd = tmpB;   // previous plane's buffer

    auto prefetch = [&](int pn) {
        const int dn = od0 - RAD + pn;
        if (p1act && (pn < NPLANES) && ((unsigned)dn < (unsigned)DD)) {
            const size_t pbv = (size_t)dn * (HH * WW) + rowoff;
#pragma unroll
            for (int j = 0; j < 5; ++j) {
                const int gc = gc0 + 4 * j;
                f4 za = (f4)0.f, zb = (f4)0.f;
                if (rowok && gc >= 0 && gc <= WW - 4) {
                    za = *(const f4*)(base1 + pbv + gc);
                    zb = *(const f4*)(base2 + pbv + gc);
                }
                pa[j] = za; pb[j] = zb;
            }
        }
    };

    prefetch(0);   // preamble: plane 0

    int pcbase = 0;
    auto body = [&](auto uc) {
        constexpr int U = decltype(uc)::value;
        const int p = pcbase + U;
        const int d = od0 - RAD + p;
        const bool dval = (p < NPLANES) && ((unsigned)d < (unsigned)DD);  // uniform

        // Phase 1: W-direction conv of the 4 transformed fields (52 tasks/wave).
        if (dval && p1act) {
            f2 q0[4], q1[4];   // q0 -> output cols (0,1); q1 -> (2,3)
#pragma unroll
            for (int st = 0; st < 4; ++st) { q0[st] = 0.f; q1[st] = 0.f; }
#pragma unroll
            for (int j = 0; j < 5; ++j) {
#pragma unroll
                for (int ii = 0; ii < 4; ++ii) {
                    const int i = 4 * j + ii;          // window col 0..19; use 3..16
                    if (i < 3 || i > 16) continue;
                    const float av = pa[j][ii], bv = pb[j][ii];
                    const float uv = av + bv, vv = av - bv;
                    const float uu = uv * uv, w2 = vv * vv;
                    const f2 w01 = { gp.gg[2*(i-1)], gp.gg[2*(i-1)+1] };
                    const f2 w23 = { gp.gg[2*(i-3)], gp.gg[2*(i-3)+1] };
                    q0[0] += w01 * uv;   q1[0] += w23 * uv;
                    q0[1] += w01 * vv;   q1[1] += w23 * vv;
                    q0[2] += w01 * uu;   q1[2] += w23 * uu;
                    q0[3] += w01 * w2;   q1[3] += w23 * w2;
                }
            }
            float* tw = twr + p1r * TS + 4 * p1q;      // 16B-aligned store base
#pragma unroll
            for (int st = 0; st < 4; ++st) {
                f4 v;
                v[0] = q0[st][0]; v[1] = q0[st][1];
                v[2] = q1[st][0]; v[3] = q1[st][1];
                *(f4*)(tw + st * STAT) = v;
            }
        }

        // Prefetch plane p+1; its waitcnt lands at first use in the next body.
        prefetch(p + 1);

        // Phase 2: H-direction conv (f2, conflict-free) + static-slot D scatter.
        if (dval) {
            // Order only LDS traffic; no vmcnt drain (prefetch completes later).
            asm volatile("s_waitcnt lgkmcnt(0)\n\ts_barrier" ::: "memory");
            f2 PU = 0.f, PV = 0.f, PA = 0.f, PB = 0.f;
            const float* tb = twr + (ty * TS + 2 * xc);
#pragma unroll
            for (int k = 0; k < KK; ++k) {
                const float w = gp.gg[2 * (k + 2)];    // scalar tap from SGPR
                const int o = k * TS;
                PU += w * *(const f2*)(tb + 0*STAT + o);
                PV += w * *(const f2*)(tb + 1*STAT + o);
                PA += w * *(const f2*)(tb + 2*STAT + o);
                PB += w * *(const f2*)(tb + 3*STAT + o);
            }
#pragma unroll
            for (int t = 0; t < KK; ++t) {
                constexpr int base = U + 22;
                const int s = (base - t) % 11;         // compile-time slot fold
                const float w = gp.gg[2 * (t + 2)];
                aU[s] += w * PU;
                aV[s] += w * PV;
                aA[s] += w * PA;
                aB[s] += w * PB;
            }
        }

        // Emit output plane q = p-10 from slot (U+1)%11, then clear the slot.
        constexpr int e = (U + 1) % 11;
        if (p >= 2 * RAD && p < NPLANES) {
            f2 Uv = aU[e], Vv = aV[e], Av = aA[e], Bv = aB[e];
            f2 U2 = Uv * Uv, V2 = Vv * Vv;
            f2 m12  = 0.25f * (U2 - V2);    // mu1*mu2
            f2 msum = 0.50f * (U2 + V2);    // mu1^2 + mu2^2
            f2 e12  = 0.25f * (Av - Bv);    // E[x1 x2]
            f2 esum = 0.50f * (Av + Bv);    // E[x1^2] + E[x2^2]
            f2 sg12 = e12 - m12;
            f2 sgsum = esum - msum;
            const float C1c = 0.0001f, C2c = 0.0009f;
            f2 num = (2.f * m12 + C1c) * (2.f * sg12 + C2c);
            f2 den = (msum + C1c) * (sgsum + C2c);
            lsum += num / den;
        }
        aU[e] = 0.f; aV[e] = 0.f; aA[e] = 0.f; aB[e] = 0.f;

        float* t = twr; twr = trd; trd = t;   // swap plane buffers
    };

    for (pcbase = 0; pcbase < 44; pcbase += 11) {
        body(ic<0>{});
        body(ic<1>{});
        body(ic<2>{});
        body(ic<3>{});
        body(ic<4>{});
        body(ic<5>{});
        body(ic<6>{});
        body(ic<7>{});
        body(ic<8>{});
        body(ic<9>{});
        body(ic<10>{});
    }

    // Reduction: wave shuffle -> LDS -> one atomic per block.
    float v = lsum.x + lsum.y;
#pragma unroll
    for (int off = 32; off > 0; off >>= 1)
        v += __shfl_down(v, off, 64);
    if ((tid & 63) == 0) wsum[tid >> 6] = v;
    __syncthreads();
    if (tid == 0) {
        const float inv_n = 1.0f / ((float)BB * DD * HH * WW);
        atomicAdd(out, (wsum[0] + wsum[1]) * inv_n);
    }
}

extern "C" void kernel_launch(void* const* d_in, const int* in_sizes, int n_in,
                              void* d_out, int out_size, void* d_ws, size_t ws_size,
                              hipStream_t stream) {
    const float* img1 = (const float*)d_in[0];
    const float* img2 = (const float*)d_in[1];
    float* out = (float*)d_out;

    double gd[KK], sum = 0.0;
    for (int i = 0; i < KK; ++i) {
        double x = (double)(i - KK / 2);
        gd[i] = exp(-(x * x) / (2.0 * 1.5 * 1.5));
        sum += gd[i];
    }
    float gf[KK];
    for (int i = 0; i < KK; ++i) gf[i] = (float)(gd[i] / sum);

    GaussP gp;
    for (int x = 0; x < 16; ++x) {
        const int j0 = x - 2, j1 = x - 3;
        gp.gg[2 * x]     = (j0 >= 0 && j0 < KK) ? gf[j0] : 0.0f;
        gp.gg[2 * x + 1] = (j1 >= 0 && j1 < KK) ? gf[j1] : 0.0f;
    }

    hipMemsetAsync(d_out, 0, sizeof(float), stream);

    dim3 grid(10 * 10 * NDCH * BB);   // 2000 blocks; % 8 XCDs == 0 (bijective swizzle)
    dim3 block(128);
    hipLaunchKernelGGL(ssim3d_kernel, grid, block, 0, stream,
                       img1, img2, out, gp);
}

// Round 13
// 321.917 us; speedup vs baseline: 1.1236x; 1.1236x over previous
//
#include <hip/hip_runtime.h>
#include <math.h>
#include <type_traits>

typedef float f2 __attribute__((ext_vector_type(2)));
typedef float f4 __attribute__((ext_vector_type(4)));

#define DD 160
#define HH 160
#define WW 160
#define BB 4
#define KK 11
#define RAD 5
#define TH 16
#define TW 8
#define DCH 32
#define NPLANES (DCH + 2 * RAD)   // 42 planes per tile (loop padded to 44 = 4*11)
#define NDCH (DD / DCH)           // 5 depth chunks
#define HALO_H (TH + 2 * RAD)     // 26 halo rows
#define TS 24                     // tmp row stride: f4/b64 aligned; 16x4 b64 reads
                                  // land 4 lanes/bank-pair uniformly (both halves)
#define STAT (HALO_H * TS)        // 624 floats per convolved field plane

// Kernarg weight-pair table: gg[2x] = G(x-2), gg[2x+1] = G(x-3), where G(j) is
// the Gaussian tap for j in [0,10] and 0 outside. Scalar tap g[k] = gg[2*(k+2)].
struct GaussP { float gg[32]; };

template <int N> using ic = std::integral_constant<int, N>;

// INDEPENDENT-WAVE version of the R11 champion: 64-thread blocks, one wave owns
// a full 16x8x32 tile -> NO inter-wave barrier (only the lgkmcnt(0) compiler
// fence, R7-proven). Co-resident waves come from independent blocks at
// independent pipeline phases -> stalls overlap instead of synchronizing.
// R7's three faults fixed: (1) LDS = 19968 B exactly -> 8 blocks/CU = 159.7 KB
// fits the 160 KB pool (R7: 20992B x 8 > 160KB -> 7 blocks, 16% occupancy);
// (2) TS=24 replaces the conflict-implicated TS=20; (3) 4-stat transform +
// XCD-chunked swizzle carried over (R7 predated both).
__global__ __launch_bounds__(64, 2)
void ssim3d_kernel(const float* __restrict__ img1,
                   const float* __restrict__ img2,
                   float* __restrict__ out, GaussP gp)
{
    __shared__ float tmp[2][4 * STAT];   // plane double buffer, 19968 B total

    const int tid = threadIdx.x;        // 64 threads = 1 wave
    const int xc = tid & 3;             // phase-2: col pair 2xc, 2xc+1 (of 8 cols)
    const int ty = tid >> 2;            // phase-2: row 0..15
    const int p1r = tid >> 1;           // phase-1: halo row 0..25 (tid < 52)
    const int p1q = tid & 1;            // phase-1: quad (4 cols) index
    const bool p1act = tid < 52;

    // XCD-chunked swizzle (bijective: 4000 blocks, 4000 % 8 == 0, 500/XCD).
    const int blk0 = blockIdx.x;
    const int blk = (blk0 & 7) * 500 + (blk0 >> 3);
    const int bw = blk % 20;
    const int bh = (blk / 20) % 10;
    const int bd = (blk / 200) % NDCH;
    const int bb = blk / 1000;

    const int oh0 = bh * TH, ow0 = bw * TW, od0 = bd * DCH;
    const float* base1 = img1 + (size_t)bb * DD * HH * WW;
    const float* base2 = img2 + (size_t)bb * DD * HH * WW;

    // Static D-ring: slot s accumulates output plane q with q % 11 == s.
    f2 aU[KK], aV[KK], aA[KK], aB[KK];
#pragma unroll
    for (int i = 0; i < KK; ++i) { aU[i]=0.f; aV[i]=0.f; aA[i]=0.f; aB[i]=0.f; }

    f2 lsum = 0.f;

    // Phase-1 per-thread constants.
    const int gh = oh0 - RAD + p1r;
    const bool rowok = p1act && ((unsigned)gh < (unsigned)HH);
    const int gc0 = ow0 + 4 * p1q - 8;                    // first loaded col, 16B aligned
    const size_t rowoff = (size_t)((unsigned)gh < (unsigned)HH ? gh : 0) * WW;

    // Register prefetch for the next plane (20 cols per task, both images).
    f4 pa[5], pb[5];
#pragma unroll
    for (int j = 0; j < 5; ++j) { pa[j] = (f4)0.f; pb[j] = (f4)0.f; }

    auto prefetch = [&](int pn) {
        const int dn = od0 - RAD + pn;
        if (p1act && (pn < NPLANES) && ((unsigned)dn < (unsigned)DD)) {
            const size_t pbv = (size_t)dn * (HH * WW) + rowoff;
#pragma unroll
            for (int j = 0; j < 5; ++j) {
                const int gc = gc0 + 4 * j;
                f4 za = (f4)0.f, zb = (f4)0.f;
                if (rowok && gc >= 0 && gc <= WW - 4) {
                    za = *(const f4*)(base1 + pbv + gc);
                    zb = *(const f4*)(base2 + pbv + gc);
                }
                pa[j] = za; pb[j] = zb;
            }
        }
    };

    prefetch(0);   // preamble: plane 0

    int pcbase = 0;
    auto body = [&](auto uc) {
        constexpr int U = decltype(uc)::value;
        const int p = pcbase + U;
        const int d = od0 - RAD + p;
        const bool dval = (p < NPLANES) && ((unsigned)d < (unsigned)DD);  // uniform

        // Phase 1: W-direction conv of the 4 transformed fields (52 tasks/wave).
        if (dval && p1act) {
            f2 q0[4], q1[4];   // q0 -> output cols (0,1); q1 -> (2,3) of this quad
#pragma unroll
            for (int st = 0; st < 4; ++st) { q0[st] = 0.f; q1[st] = 0.f; }
#pragma unroll
            for (int j = 0; j < 5; ++j) {
#pragma unroll
                for (int ii = 0; ii < 4; ++ii) {
                    const int i = 4 * j + ii;          // window col 0..19; use 3..16
                    if (i < 3 || i > 16) continue;
                    const float av = pa[j][ii], bv = pb[j][ii];
                    const float uv = av + bv, vv = av - bv;
                    const float uu = uv * uv, w2 = vv * vv;
                    const f2 w01 = { gp.gg[2*(i-1)], gp.gg[2*(i-1)+1] };
                    const f2 w23 = { gp.gg[2*(i-3)], gp.gg[2*(i-3)+1] };
                    q0[0] += w01 * uv;   q1[0] += w23 * uv;
                    q0[1] += w01 * vv;   q1[1] += w23 * vv;
                    q0[2] += w01 * uu;   q1[2] += w23 * uu;
                    q0[3] += w01 * w2;   q1[3] += w23 * w2;
                }
            }
            float* tw = tmp[p & 1] + p1r * TS + 4 * p1q;   // 16B-aligned store base
#pragma unroll
            for (int st = 0; st < 4; ++st) {
                f4 v;
                v[0] = q0[st][0]; v[1] = q0[st][1];
                v[2] = q1[st][0]; v[3] = q1[st][1];
                *(f4*)(tw + st * STAT) = v;
            }
        }

        // Prefetch plane p+1; its waitcnt lands at first use in the next body.
        prefetch(p + 1);

        // Phase 2: H-direction conv (f2) + static-slot D scatter.
        if (dval) {
            // Single wave: in-order DS pipe + this compiler fence order the
            // phase-1 writes against the reads. No s_barrier, no vmcnt drain.
            asm volatile("s_waitcnt lgkmcnt(0)" ::: "memory");
            f2 PU = 0.f, PV = 0.f, PA = 0.f, PB = 0.f;
            const float* tb = tmp[p & 1] + (ty * TS + 2 * xc);
#pragma unroll
            for (int k = 0; k < KK; ++k) {
                const float w = gp.gg[2 * (k + 2)];    // scalar tap from SGPR
                const int o = k * TS;
                PU += w * *(const f2*)(tb + 0*STAT + o);
                PV += w * *(const f2*)(tb + 1*STAT + o);
                PA += w * *(const f2*)(tb + 2*STAT + o);
                PB += w * *(const f2*)(tb + 3*STAT + o);
            }
#pragma unroll
            for (int t = 0; t < KK; ++t) {
                constexpr int base = U + 22;
                const int s = (base - t) % 11;         // compile-time slot fold
                const float w = gp.gg[2 * (t + 2)];
                aU[s] += w * PU;
                aV[s] += w * PV;
                aA[s] += w * PA;
                aB[s] += w * PB;
            }
        }

        // Emit output plane q = p-10 from slot (U+1)%11, then clear the slot.
        constexpr int e = (U + 1) % 11;
        if (p >= 2 * RAD && p < NPLANES) {
            f2 Uv = aU[e], Vv = aV[e], Av = aA[e], Bv = aB[e];
            f2 U2 = Uv * Uv, V2 = Vv * Vv;
            f2 m12  = 0.25f * (U2 - V2);    // mu1*mu2
            f2 msum = 0.50f * (U2 + V2);    // mu1^2 + mu2^2
            f2 e12  = 0.25f * (Av - Bv);    // E[x1 x2]
            f2 esum = 0.50f * (Av + Bv);    // E[x1^2] + E[x2^2]
            f2 sg12 = e12 - m12;
            f2 sgsum = esum - msum;
            const float C1c = 0.0001f, C2c = 0.0009f;
            f2 num = (2.f * m12 + C1c) * (2.f * sg12 + C2c);
            f2 den = (msum + C1c) * (sgsum + C2c);
            lsum += num / den;
        }
        aU[e] = 0.f; aV[e] = 0.f; aA[e] = 0.f; aB[e] = 0.f;
    };

    for (pcbase = 0; pcbase < 44; pcbase += 11) {
        body(ic<0>{});
        body(ic<1>{});
        body(ic<2>{});
        body(ic<3>{});
        body(ic<4>{});
        body(ic<5>{});
        body(ic<6>{});
        body(ic<7>{});
        body(ic<8>{});
        body(ic<9>{});
        body(ic<10>{});
    }

    // Reduction: single-wave shuffle -> one atomic per block.
    float v = lsum.x + lsum.y;
#pragma unroll
    for (int off = 32; off > 0; off >>= 1)
        v += __shfl_down(v, off, 64);
    if (tid == 0) {
        const float inv_n = 1.0f / ((float)BB * DD * HH * WW);
        atomicAdd(out, v * inv_n);
    }
}

extern "C" void kernel_launch(void* const* d_in, const int* in_sizes, int n_in,
                              void* d_out, int out_size, void* d_ws, size_t ws_size,
                              hipStream_t stream) {
    const float* img1 = (const float*)d_in[0];
    const float* img2 = (const float*)d_in[1];
    float* out = (float*)d_out;

    double gd[KK], sum = 0.0;
    for (int i = 0; i < KK; ++i) {
        double x = (double)(i - KK / 2);
        gd[i] = exp(-(x * x) / (2.0 * 1.5 * 1.5));
        sum += gd[i];
    }
    float gf[KK];
    for (int i = 0; i < KK; ++i) gf[i] = (float)(gd[i] / sum);

    GaussP gp;
    for (int x = 0; x < 16; ++x) {
        const int j0 = x - 2, j1 = x - 3;
        gp.gg[2 * x]     = (j0 >= 0 && j0 < KK) ? gf[j0] : 0.0f;
        gp.gg[2 * x + 1] = (j1 >= 0 && j1 < KK) ? gf[j1] : 0.0f;
    }

    hipMemsetAsync(d_out, 0, sizeof(float), stream);

    dim3 grid(20 * 10 * NDCH * BB);   // 4000 blocks; % 8 XCDs == 0 (bijective swizzle)
    dim3 block(64);                   // 1 wave per block
    hipLaunchKernelGGL(ssim3d_kernel, grid, block, 0, stream,
                       img1, img2, out, gp);
}